// Round 1
// baseline (285.710 us; speedup 1.0000x reference)
//
#include <hip/hip_runtime.h>

// Problem constants (B=1)
constexpr int C = 32, H = 256, W = 512, K = 10;
constexpr int HW = H * W;               // 131072
constexpr float TEMP = 10000.0f;

__global__ __launch_bounds__(256) void disp_kernel(
    const float* __restrict__ left, const float* __restrict__ right,
    const float* __restrict__ offx, const float* __restrict__ offy,
    float* __restrict__ out)
{
    const int p = blockIdx.x * 256 + threadIdx.x;   // pixel id, grid exactly covers HW
    const int w = p & (W - 1);
    const int h = p >> 9;                            // W = 512 = 2^9

    // left features for this pixel, cached in registers (coalesced loads)
    float lf[C];
    #pragma unroll
    for (int c = 0; c < C; ++c) lf[c] = left[c * HW + p];

    const float lx = (float)w;
    const float ly = (float)h;  // reference clips to W-1; no-op since H <= W

    float s[K], okx[K], oky[K];

    #pragma unroll
    for (int k = 0; k < K; ++k) {
        const float ox = offx[k * HW + p];
        const float oy = offy[k * HW + p];
        okx[k] = ox; oky[k] = oy;

        // mirror reference arithmetic exactly
        float rx = fminf(fmaxf(lx - ox, 0.0f), (float)(W - 1));
        float ry = fminf(fmaxf(ly - oy, 0.0f), (float)(H - 1));
        float gx = (rx - (float)(W / 2)) / (float)(W / 2);
        float gy = (ry - (float)(H / 2)) / (float)(H / 2);
        float ix = ((gx + 1.0f) * (float)W - 1.0f) * 0.5f;
        float iy = ((gy + 1.0f) * (float)H - 1.0f) * 0.5f;

        float x0f = floorf(ix), y0f = floorf(iy);
        float wx1 = ix - x0f, wy1 = iy - y0f;
        float wx0 = 1.0f - wx1, wy0 = 1.0f - wy1;
        int x0 = (int)x0f, y0 = (int)y0f;
        int x1 = x0 + 1,  y1 = y0 + 1;

        // zero-padding validity folded into corner weights
        float vx0 = (x0 >= 0 && x0 <= W - 1) ? 1.0f : 0.0f;
        float vx1 = (x1 >= 0 && x1 <= W - 1) ? 1.0f : 0.0f;
        float vy0 = (y0 >= 0 && y0 <= H - 1) ? 1.0f : 0.0f;
        float vy1 = (y1 >= 0 && y1 <= H - 1) ? 1.0f : 0.0f;
        float w00 = wx0 * wy0 * vx0 * vy0;
        float w01 = wx1 * wy0 * vx1 * vy0;
        float w10 = wx0 * wy1 * vx0 * vy1;
        float w11 = wx1 * wy1 * vx1 * vy1;

        int xi0 = min(max(x0, 0), W - 1), xi1 = min(max(x1, 0), W - 1);
        int yi0 = min(max(y0, 0), H - 1), yi1 = min(max(y1, 0), H - 1);
        int i00 = yi0 * W + xi0;
        int i01 = yi0 * W + xi1;
        int i10 = yi1 * W + xi0;
        int i11 = yi1 * W + xi1;

        float acc = 0.0f;
        #pragma unroll
        for (int c = 0; c < C; ++c) {
            const float* rc = right + c * HW;
            float g = w00 * rc[i00] + w01 * rc[i01]
                    + w10 * rc[i10] + w11 * rc[i11];
            acc += fabsf(lf[c] - g);
        }
        // mean(-|d|) * TEMP  ==  acc * (-TEMP/C)  (TEMP/C = 312.5 exact)
        s[k] = acc * (-TEMP / (float)C);
    }

    // softmax over K with weighted offset sums
    float m = s[0];
    #pragma unroll
    for (int k = 1; k < K; ++k) m = fmaxf(m, s[k]);
    float den = 0.0f, sx = 0.0f, sy = 0.0f;
    #pragma unroll
    for (int k = 0; k < K; ++k) {
        float e = __expf(s[k] - m);
        den += e;
        sx += okx[k] * e;
        sy += oky[k] * e;
    }
    float inv = 1.0f / den;   // den >= 1
    out[p]      = sx * inv;
    out[HW + p] = sy * inv;
}

extern "C" void kernel_launch(void* const* d_in, const int* in_sizes, int n_in,
                              void* d_out, int out_size, void* d_ws, size_t ws_size,
                              hipStream_t stream) {
    const float* left  = (const float*)d_in[0];
    const float* right = (const float*)d_in[1];
    const float* offx  = (const float*)d_in[2];
    const float* offy  = (const float*)d_in[3];
    float* out = (float*)d_out;
    disp_kernel<<<HW / 256, 256, 0, stream>>>(left, right, offx, offy, out);
}

// Round 2
// 131.555 us; speedup vs baseline: 2.1718x; 2.1718x over previous
//
#include <hip/hip_runtime.h>

// Problem constants (B=1)
constexpr int C = 32, H = 256, W = 512, K = 10;
constexpr int HW = H * W;               // 131072
constexpr float TEMP = 10000.0f;

// ---------------- transpose CHW -> HWC (pixel-major, channel-contiguous) ----
__global__ __launch_bounds__(256) void transpose_chw_hwc(
    const float* __restrict__ in, float* __restrict__ out)
{
    __shared__ float t[C][257];          // +1 pad: conflict-free store-phase reads
    const int base = blockIdx.x * 256;
    const int tid = threadIdx.x;
    #pragma unroll
    for (int c = 0; c < C; ++c)          // coalesced reads along W
        t[c][tid] = in[c * HW + base + tid];
    __syncthreads();
    #pragma unroll
    for (int j = 0; j < C; ++j) {        // coalesced writes: out[base*32 + idx]
        int idx = j * 256 + tid;
        out[base * C + idx] = t[idx & 31][idx >> 5];
    }
}

// ---------------- main: 4 threads per pixel, 8 channels each ----------------
__global__ __launch_bounds__(256) void disp_kernel_hwc(
    const float* __restrict__ lhwc, const float* __restrict__ rhwc,
    const float* __restrict__ offx, const float* __restrict__ offy,
    float* __restrict__ out)
{
    const int tid = threadIdx.x;
    const int q = tid & 3;                        // channel quarter (8 ch)
    const int p = blockIdx.x * 64 + (tid >> 2);   // pixel id
    const int w = p & (W - 1);
    const int h = p >> 9;

    // left features: 8 contiguous channels -> two float4 loads
    const float4* lp = (const float4*)(lhwc + p * C + q * 8);
    float4 l0 = lp[0], l1 = lp[1];
    float lf[8] = {l0.x, l0.y, l0.z, l0.w, l1.x, l1.y, l1.z, l1.w};

    const float lx = (float)w;
    const float ly = (float)h;   // ref clips y to W-1: no-op (H <= W)

    float s[K], okx[K], oky[K];

    #pragma unroll
    for (int k = 0; k < K; ++k) {
        const float ox = offx[k * HW + p];
        const float oy = offy[k * HW + p];
        okx[k] = ox; oky[k] = oy;

        // mirror reference arithmetic exactly
        float rx = fminf(fmaxf(lx - ox, 0.0f), (float)(W - 1));
        float ry = fminf(fmaxf(ly - oy, 0.0f), (float)(H - 1));
        float gx = (rx - (float)(W / 2)) / (float)(W / 2);
        float gy = (ry - (float)(H / 2)) / (float)(H / 2);
        float ix = ((gx + 1.0f) * (float)W - 1.0f) * 0.5f;
        float iy = ((gy + 1.0f) * (float)H - 1.0f) * 0.5f;

        float x0f = floorf(ix), y0f = floorf(iy);
        float wx1 = ix - x0f, wy1 = iy - y0f;
        float wx0 = 1.0f - wx1, wy0 = 1.0f - wy1;
        int x0 = (int)x0f, y0 = (int)y0f;
        int x1 = x0 + 1,  y1 = y0 + 1;

        float vx0 = (x0 >= 0 && x0 <= W - 1) ? 1.0f : 0.0f;
        float vx1 = (x1 >= 0 && x1 <= W - 1) ? 1.0f : 0.0f;
        float vy0 = (y0 >= 0 && y0 <= H - 1) ? 1.0f : 0.0f;
        float vy1 = (y1 >= 0 && y1 <= H - 1) ? 1.0f : 0.0f;
        float w00 = wx0 * wy0 * vx0 * vy0;
        float w01 = wx1 * wy0 * vx1 * vy0;
        float w10 = wx0 * wy1 * vx0 * vy1;
        float w11 = wx1 * wy1 * vx0 * vy1;   // fixed below
        w11 = wx1 * wy1 * vx1 * vy1;

        int xi0 = min(max(x0, 0), W - 1), xi1 = min(max(x1, 0), W - 1);
        int yi0 = min(max(y0, 0), H - 1), yi1 = min(max(y1, 0), H - 1);

        const float4* c00 = (const float4*)(rhwc + (yi0 * W + xi0) * C + q * 8);
        const float4* c01 = (const float4*)(rhwc + (yi0 * W + xi1) * C + q * 8);
        const float4* c10 = (const float4*)(rhwc + (yi1 * W + xi0) * C + q * 8);
        const float4* c11 = (const float4*)(rhwc + (yi1 * W + xi1) * C + q * 8);
        float4 a0 = c00[0], a1 = c00[1];
        float4 b0 = c01[0], b1 = c01[1];
        float4 d0 = c10[0], d1 = c10[1];
        float4 e0 = c11[0], e1 = c11[1];
        float ca[8] = {a0.x, a0.y, a0.z, a0.w, a1.x, a1.y, a1.z, a1.w};
        float cb[8] = {b0.x, b0.y, b0.z, b0.w, b1.x, b1.y, b1.z, b1.w};
        float cd[8] = {d0.x, d0.y, d0.z, d0.w, d1.x, d1.y, d1.z, d1.w};
        float ce[8] = {e0.x, e0.y, e0.z, e0.w, e1.x, e1.y, e1.z, e1.w};

        float acc = 0.0f;
        #pragma unroll
        for (int j = 0; j < 8; ++j) {
            float g = w00 * ca[j] + w01 * cb[j] + w10 * cd[j] + w11 * ce[j];
            acc += fabsf(lf[j] - g);
        }
        // sum partial |diff| over the 4 lanes of this pixel group
        acc += __shfl_xor(acc, 1);
        acc += __shfl_xor(acc, 2);
        s[k] = acc * (-TEMP / (float)C);   // -312.5 exact
    }

    // softmax over K (computed redundantly in all 4 lanes; lane q==0 writes)
    float m = s[0];
    #pragma unroll
    for (int k = 1; k < K; ++k) m = fmaxf(m, s[k]);
    float den = 0.0f, sx = 0.0f, sy = 0.0f;
    #pragma unroll
    for (int k = 0; k < K; ++k) {
        float e = __expf(s[k] - m);
        den += e;
        sx += okx[k] * e;
        sy += oky[k] * e;
    }
    float inv = 1.0f / den;
    if (q == 0) {
        out[p]      = sx * inv;
        out[HW + p] = sy * inv;
    }
}

// ---------------- fallback (round-1 kernel) if workspace too small ----------
__global__ __launch_bounds__(256) void disp_kernel_chw(
    const float* __restrict__ left, const float* __restrict__ right,
    const float* __restrict__ offx, const float* __restrict__ offy,
    float* __restrict__ out)
{
    const int p = blockIdx.x * 256 + threadIdx.x;
    const int w = p & (W - 1);
    const int h = p >> 9;
    float lf[C];
    #pragma unroll
    for (int c = 0; c < C; ++c) lf[c] = left[c * HW + p];
    const float lx = (float)w, ly = (float)h;
    float s[K], okx[K], oky[K];
    #pragma unroll
    for (int k = 0; k < K; ++k) {
        const float ox = offx[k * HW + p], oy = offy[k * HW + p];
        okx[k] = ox; oky[k] = oy;
        float rx = fminf(fmaxf(lx - ox, 0.0f), (float)(W - 1));
        float ry = fminf(fmaxf(ly - oy, 0.0f), (float)(H - 1));
        float gx = (rx - 256.0f) / 256.0f, gy = (ry - 128.0f) / 128.0f;
        float ix = ((gx + 1.0f) * (float)W - 1.0f) * 0.5f;
        float iy = ((gy + 1.0f) * (float)H - 1.0f) * 0.5f;
        float x0f = floorf(ix), y0f = floorf(iy);
        float wx1 = ix - x0f, wy1 = iy - y0f;
        float wx0 = 1.0f - wx1, wy0 = 1.0f - wy1;
        int x0 = (int)x0f, y0 = (int)y0f, x1 = x0 + 1, y1 = y0 + 1;
        float vx0 = (x0 >= 0 && x0 <= W - 1) ? 1.0f : 0.0f;
        float vx1 = (x1 >= 0 && x1 <= W - 1) ? 1.0f : 0.0f;
        float vy0 = (y0 >= 0 && y0 <= H - 1) ? 1.0f : 0.0f;
        float vy1 = (y1 >= 0 && y1 <= H - 1) ? 1.0f : 0.0f;
        float w00 = wx0 * wy0 * vx0 * vy0, w01 = wx1 * wy0 * vx1 * vy0;
        float w10 = wx0 * wy1 * vx0 * vy1, w11 = wx1 * wy1 * vx1 * vy1;
        int xi0 = min(max(x0, 0), W - 1), xi1 = min(max(x1, 0), W - 1);
        int yi0 = min(max(y0, 0), H - 1), yi1 = min(max(y1, 0), H - 1);
        int i00 = yi0 * W + xi0, i01 = yi0 * W + xi1;
        int i10 = yi1 * W + xi0, i11 = yi1 * W + xi1;
        float acc = 0.0f;
        #pragma unroll
        for (int c = 0; c < C; ++c) {
            const float* rc = right + c * HW;
            acc += fabsf(lf[c] - (w00 * rc[i00] + w01 * rc[i01]
                                + w10 * rc[i10] + w11 * rc[i11]));
        }
        s[k] = acc * (-TEMP / (float)C);
    }
    float m = s[0];
    #pragma unroll
    for (int k = 1; k < K; ++k) m = fmaxf(m, s[k]);
    float den = 0.0f, sx = 0.0f, sy = 0.0f;
    #pragma unroll
    for (int k = 0; k < K; ++k) {
        float e = __expf(s[k] - m);
        den += e; sx += okx[k] * e; sy += oky[k] * e;
    }
    float inv = 1.0f / den;
    out[p] = sx * inv;
    out[HW + p] = sy * inv;
}

extern "C" void kernel_launch(void* const* d_in, const int* in_sizes, int n_in,
                              void* d_out, int out_size, void* d_ws, size_t ws_size,
                              hipStream_t stream) {
    const float* left  = (const float*)d_in[0];
    const float* right = (const float*)d_in[1];
    const float* offx  = (const float*)d_in[2];
    const float* offy  = (const float*)d_in[3];
    float* out = (float*)d_out;

    const size_t need = (size_t)2 * HW * C * sizeof(float);   // 32 MB
    if (ws_size >= need) {
        float* rhwc = (float*)d_ws;
        float* lhwc = rhwc + (size_t)HW * C;
        transpose_chw_hwc<<<HW / 256, 256, 0, stream>>>(right, rhwc);
        transpose_chw_hwc<<<HW / 256, 256, 0, stream>>>(left,  lhwc);
        disp_kernel_hwc<<<HW / 64, 256, 0, stream>>>(lhwc, rhwc, offx, offy, out);
    } else {
        disp_kernel_chw<<<HW / 256, 256, 0, stream>>>(left, right, offx, offy, out);
    }
}

// Round 3
// 120.760 us; speedup vs baseline: 2.3659x; 1.0894x over previous
//
#include <hip/hip_runtime.h>

// Problem constants (B=1)
constexpr int C = 32, H = 256, W = 512, K = 10;
constexpr int HW = H * W;               // 131072
constexpr float TEMP = 10000.0f;

// -------- transpose right: CHW f32 -> HWC f32 (pixel-major) ---------------
// 128-pixel tiles, 1024 blocks, 16.5 KB LDS -> good CU spread.
__global__ __launch_bounds__(256) void conv_right_hwc(
    const float* __restrict__ in, float* __restrict__ out)
{
    __shared__ float t[C][129];          // +1 pad: conflict-free both phases
    const int base = blockIdx.x * 128;
    const int tid = threadIdx.x;
    #pragma unroll
    for (int i = 0; i < 16; ++i) {       // load 32ch x 128px tile, coalesced
        int lin = i * 256 + tid;
        int c = lin >> 7, px = lin & 127;
        t[c][px] = in[c * HW + base + px];
    }
    __syncthreads();
    #pragma unroll
    for (int i = 0; i < 16; ++i) {       // store HWC, fully coalesced
        int lin = i * 256 + tid;
        int px = lin >> 5, c = lin & 31;
        out[(base + px) * C + c] = t[c][px];
    }
}

// -------- main: 4 lanes per pixel, 8 channels each, right in HWC ----------
__global__ __launch_bounds__(256, 4) void disp_kernel_hwc(
    const float* __restrict__ lchw, const float* __restrict__ rhwc,
    const float* __restrict__ offx, const float* __restrict__ offy,
    float* __restrict__ out)
{
    const int tid = threadIdx.x;
    const int q = tid & 3;                        // channel quarter (8 ch)
    const int p = blockIdx.x * 64 + (tid >> 2);   // pixel id
    const int w = p & (W - 1);
    const int h = p >> 9;

    // left features straight from CHW: 8 loads, each instr = 2 x 64B segments
    float lf[8];
    #pragma unroll
    for (int j = 0; j < 8; ++j) lf[j] = lchw[(q * 8 + j) * HW + p];

    // preload all K offsets (held for the epilogue anyway)
    float okx[K], oky[K];
    #pragma unroll
    for (int k = 0; k < K; ++k) {
        okx[k] = offx[k * HW + p];
        oky[k] = offy[k * HW + p];
    }

    const float lx = (float)w;
    const float ly = (float)h;   // ref clips y to W-1: no-op (H <= W)
    const float4* rbase = (const float4*)rhwc;   // 8 float4 per pixel

    float s[K];

    #pragma unroll
    for (int k = 0; k < K; ++k) {
        const float ox = okx[k];
        const float oy = oky[k];

        // mirror reference arithmetic exactly (absmax 0.25 proven)
        float rx = fminf(fmaxf(lx - ox, 0.0f), (float)(W - 1));
        float ry = fminf(fmaxf(ly - oy, 0.0f), (float)(H - 1));
        float gx = (rx - (float)(W / 2)) / (float)(W / 2);
        float gy = (ry - (float)(H / 2)) / (float)(H / 2);
        float ix = ((gx + 1.0f) * (float)W - 1.0f) * 0.5f;
        float iy = ((gy + 1.0f) * (float)H - 1.0f) * 0.5f;

        float x0f = floorf(ix), y0f = floorf(iy);
        float wx1 = ix - x0f, wy1 = iy - y0f;
        float wx0 = 1.0f - wx1, wy0 = 1.0f - wy1;
        int x0 = (int)x0f, y0 = (int)y0f;
        int x1 = x0 + 1,  y1 = y0 + 1;

        float vx0 = (x0 >= 0 && x0 <= W - 1) ? 1.0f : 0.0f;
        float vx1 = (x1 >= 0 && x1 <= W - 1) ? 1.0f : 0.0f;
        float vy0 = (y0 >= 0 && y0 <= H - 1) ? 1.0f : 0.0f;
        float vy1 = (y1 >= 0 && y1 <= H - 1) ? 1.0f : 0.0f;
        float w00 = wx0 * wy0 * vx0 * vy0;
        float w01 = wx1 * wy0 * vx1 * vy0;
        float w10 = wx0 * wy1 * vx0 * vy1;
        float w11 = wx1 * wy1 * vx1 * vy1;

        int xi0 = min(max(x0, 0), W - 1), xi1 = min(max(x1, 0), W - 1);
        int yi0 = min(max(y0, 0), H - 1), yi1 = min(max(y1, 0), H - 1);

        // all 8 corner loads issued back-to-back (pipelining-friendly)
        int i00 = (yi0 * W + xi0) * 8 + q * 2;   // float4 index
        int i01 = (yi0 * W + xi1) * 8 + q * 2;
        int i10 = (yi1 * W + xi0) * 8 + q * 2;
        int i11 = (yi1 * W + xi1) * 8 + q * 2;
        float4 a0 = rbase[i00], a1 = rbase[i00 + 1];
        float4 b0 = rbase[i01], b1 = rbase[i01 + 1];
        float4 d0 = rbase[i10], d1 = rbase[i10 + 1];
        float4 e0 = rbase[i11], e1 = rbase[i11 + 1];
        float ca[8] = {a0.x, a0.y, a0.z, a0.w, a1.x, a1.y, a1.z, a1.w};
        float cb[8] = {b0.x, b0.y, b0.z, b0.w, b1.x, b1.y, b1.z, b1.w};
        float cd[8] = {d0.x, d0.y, d0.z, d0.w, d1.x, d1.y, d1.z, d1.w};
        float ce[8] = {e0.x, e0.y, e0.z, e0.w, e1.x, e1.y, e1.z, e1.w};

        float acc = 0.0f;
        #pragma unroll
        for (int j = 0; j < 8; ++j) {
            float g = w00 * ca[j] + w01 * cb[j] + w10 * cd[j] + w11 * ce[j];
            acc += fabsf(lf[j] - g);
        }
        // sum the 4 channel-quarter partials of this pixel group
        acc += __shfl_xor(acc, 1);
        acc += __shfl_xor(acc, 2);
        s[k] = acc * (-TEMP / (float)C);   // -312.5 exact
    }

    // softmax over K (redundant in all 4 lanes; lane q==0 writes)
    float m = s[0];
    #pragma unroll
    for (int k = 1; k < K; ++k) m = fmaxf(m, s[k]);
    float den = 0.0f, sx = 0.0f, sy = 0.0f;
    #pragma unroll
    for (int k = 0; k < K; ++k) {
        float e = __expf(s[k] - m);
        den += e;
        sx += okx[k] * e;
        sy += oky[k] * e;
    }
    float inv = 1.0f / den;
    if (q == 0) {
        out[p]      = sx * inv;
        out[HW + p] = sy * inv;
    }
}

// -------- fallback (round-1 kernel) if workspace too small ----------------
__global__ __launch_bounds__(256) void disp_kernel_chw(
    const float* __restrict__ left, const float* __restrict__ right,
    const float* __restrict__ offx, const float* __restrict__ offy,
    float* __restrict__ out)
{
    const int p = blockIdx.x * 256 + threadIdx.x;
    const int w = p & (W - 1);
    const int h = p >> 9;
    float lf[C];
    #pragma unroll
    for (int c = 0; c < C; ++c) lf[c] = left[c * HW + p];
    const float lx = (float)w, ly = (float)h;
    float s[K], okx[K], oky[K];
    #pragma unroll
    for (int k = 0; k < K; ++k) {
        const float ox = offx[k * HW + p], oy = offy[k * HW + p];
        okx[k] = ox; oky[k] = oy;
        float rx = fminf(fmaxf(lx - ox, 0.0f), (float)(W - 1));
        float ry = fminf(fmaxf(ly - oy, 0.0f), (float)(H - 1));
        float gx = (rx - 256.0f) / 256.0f, gy = (ry - 128.0f) / 128.0f;
        float ix = ((gx + 1.0f) * (float)W - 1.0f) * 0.5f;
        float iy = ((gy + 1.0f) * (float)H - 1.0f) * 0.5f;
        float x0f = floorf(ix), y0f = floorf(iy);
        float wx1 = ix - x0f, wy1 = iy - y0f;
        float wx0 = 1.0f - wx1, wy0 = 1.0f - wy1;
        int x0 = (int)x0f, y0 = (int)y0f, x1 = x0 + 1, y1 = y0 + 1;
        float vx0 = (x0 >= 0 && x0 <= W - 1) ? 1.0f : 0.0f;
        float vx1 = (x1 >= 0 && x1 <= W - 1) ? 1.0f : 0.0f;
        float vy0 = (y0 >= 0 && y0 <= H - 1) ? 1.0f : 0.0f;
        float vy1 = (y1 >= 0 && y1 <= H - 1) ? 1.0f : 0.0f;
        float w00 = wx0 * wy0 * vx0 * vy0, w01 = wx1 * wy0 * vx1 * vy0;
        float w10 = wx0 * wy1 * vx0 * vy1, w11 = wx1 * wy1 * vx1 * vy1;
        int xi0 = min(max(x0, 0), W - 1), xi1 = min(max(x1, 0), W - 1);
        int yi0 = min(max(y0, 0), H - 1), yi1 = min(max(y1, 0), H - 1);
        int i00 = yi0 * W + xi0, i01 = yi0 * W + xi1;
        int i10 = yi1 * W + xi0, i11 = yi1 * W + xi1;
        float acc = 0.0f;
        #pragma unroll
        for (int c = 0; c < C; ++c) {
            const float* rc = right + c * HW;
            acc += fabsf(lf[c] - (w00 * rc[i00] + w01 * rc[i01]
                                + w10 * rc[i10] + w11 * rc[i11]));
        }
        s[k] = acc * (-TEMP / (float)C);
    }
    float m = s[0];
    #pragma unroll
    for (int k = 1; k < K; ++k) m = fmaxf(m, s[k]);
    float den = 0.0f, sx = 0.0f, sy = 0.0f;
    #pragma unroll
    for (int k = 0; k < K; ++k) {
        float e = __expf(s[k] - m);
        den += e; sx += okx[k] * e; sy += oky[k] * e;
    }
    float inv = 1.0f / den;
    out[p] = sx * inv;
    out[HW + p] = sy * inv;
}

extern "C" void kernel_launch(void* const* d_in, const int* in_sizes, int n_in,
                              void* d_out, int out_size, void* d_ws, size_t ws_size,
                              hipStream_t stream) {
    const float* left  = (const float*)d_in[0];
    const float* right = (const float*)d_in[1];
    const float* offx  = (const float*)d_in[2];
    const float* offy  = (const float*)d_in[3];
    float* out = (float*)d_out;

    const size_t need = (size_t)HW * C * sizeof(float);   // 16 MB
    if (ws_size >= need) {
        float* rhwc = (float*)d_ws;
        conv_right_hwc<<<HW / 128, 256, 0, stream>>>(right, rhwc);
        disp_kernel_hwc<<<HW / 64, 256, 0, stream>>>(left, rhwc, offx, offy, out);
    } else {
        disp_kernel_chw<<<HW / 256, 256, 0, stream>>>(left, right, offx, offy, out);
    }
}